// Round 1
// 823.170 us; speedup vs baseline: 1.1094x; 1.1094x over previous
//
#include <hip/hip_runtime.h>

// Problem constants (fixed by reference): B=4, T=400, U=100, D=512, V=1024
#define Bb 4
#define Tt 400
#define Uu 100
#define Dd 512
#define Vv 1024
#define Mtot (Bb * Tt * Uu)          // 160000 rows
#define OUT_ELEMS ((size_t)Mtot * Vv) // 163,840,000
#define NT 8                          // K-tiles: 512 / 64

typedef unsigned short u16;
typedef unsigned int u32;
typedef short bf16x8 __attribute__((ext_vector_type(8)));
typedef float f32x4 __attribute__((ext_vector_type(4)));
typedef u16 u16x4 __attribute__((ext_vector_type(4)));

// float -> bf16 round-to-nearest-even (inputs finite; no NaN path needed)
__device__ __forceinline__ u16 f2bf(float x) {
    union { float f; u32 u; } v; v.f = x;
    u32 r = v.u + 0x7FFFu + ((v.u >> 16) & 1u);
    return (u16)(r >> 16);
}

// async global->LDS, 16 bytes/lane (dest must be wave-uniform base + lane*16)
__device__ __forceinline__ void async16(const void* g, void* l) {
    __builtin_amdgcn_global_load_lds(
        (const __attribute__((address_space(1))) u32*)g,
        (__attribute__((address_space(3))) u32*)l,
        16, 0, 0);
}

// ---------------- Phase 1: A[m,k] = bf16(tanh(src[b,t,k] + tgt[b,u,k])) ----
__global__ void tanh_fuse(const float* __restrict__ src,
                          const float* __restrict__ tgt,
                          u16* __restrict__ A) {
    int idx = blockIdx.x * 256 + threadIdx.x;   // 0 .. 20,479,999
    int d4 = idx & 127;                          // 512/4 = 128 float4 per row
    int m  = idx >> 7;
    int b  = m / 40000;
    int r  = m - b * 40000;
    int t  = r / 100;
    int u  = r - t * 100;
    const float4 s = ((const float4*)src)[(b * Tt + t) * 128 + d4];
    const float4 g = ((const float4*)tgt)[(b * Uu + u) * 128 + d4];
    u16x4 o;
    o.x = f2bf(tanhf(s.x + g.x));
    o.y = f2bf(tanhf(s.y + g.y));
    o.z = f2bf(tanhf(s.z + g.z));
    o.w = f2bf(tanhf(s.w + g.w));
    ((u16x4*)A)[idx] = o;
}

// ---------------- W fp32 -> bf16, plus length pass-through outputs ---------
__global__ void wconv(const float* __restrict__ W, u16* __restrict__ Wb,
                      const int* __restrict__ slen, const int* __restrict__ tlen,
                      float* __restrict__ out) {
    int idx = blockIdx.x * 256 + threadIdx.x;   // 0 .. 131071
    float4 w = ((const float4*)W)[idx];
    u16x4 o;
    o.x = f2bf(w.x); o.y = f2bf(w.y); o.z = f2bf(w.z); o.w = f2bf(w.w);
    ((u16x4*)Wb)[idx] = o;
    if (idx < 4)      out[OUT_ELEMS + idx] = (float)slen[idx];
    else if (idx < 8) out[OUT_ELEMS + idx] = (float)tlen[idx - 4];
}

// ---------------- Phase 2: 256x256 8-phase GEMM-BT (m201 template) ---------
// C[m,v] = sum_k A[m,k]*Wb[v,k] + bias[v].  8 waves (2M x 4N), per-wave 128x64.
// LDS 128 KiB: 2 bufs x {A: 2 halves x 128x64, B: same}, bf16.
// Swizzle: LDS slot s of row holds global chunk (s ^ (row&7)) — linear dest
// for global_load_lds, inverse-swizzled global source, same XOR on reads.
// Counted vmcnt(2) at K-tile boundaries only (1 half-tile stays in flight).

// stage one 128x64 half-tile: 512 threads x 2 x 16B
__device__ __forceinline__ void stg2(const u16* g, u16* l, int off0, int loff) {
    async16(g + off0,         l + loff);          // rows 0..63 of half
    async16(g + off0 + 32768, l + loff + 4096);   // rows 64..127 (64*512 elems)
}

__global__ __launch_bounds__(512, 2) void gemm8(const u16* __restrict__ A,
                                                const u16* __restrict__ Wb,
                                                const float* __restrict__ bias,
                                                float* __restrict__ out) {
    __shared__ u16 sm[65536];   // 128 KiB

    const int tid = threadIdx.x;
    // bijective XCD swizzle: 2500 wgs, q=312, r=4 (m204 formula)
    const int orig = blockIdx.x;
    const int xcd = orig & 7, loc = orig >> 3;
    const int wg = (xcd < 4 ? xcd * 313 : 1252 + (xcd - 4) * 312) + loc;
    const int bm = wg >> 2;        // 0..624
    const int bn = wg & 3;         // 0..3

    const int lane = tid & 63, wave = tid >> 6;
    const int wm = wave >> 2, wn = wave & 3;       // 2M x 4N waves
    const int l15 = lane & 15, quad = lane >> 4;
    const int sx = l15 & 7;                        // read-side swizzle key
    const int c0 = (quad ^ sx) * 8;                // kk=0 chunk offset (elems)
    const int c1 = ((4 | quad) ^ sx) * 8;          // kk=1 chunk offset

    // staging lane constants: chunk c = q*512+tid -> row=c>>3, slot=c&7
    const int srow = tid >> 3;                       // 0..63
    const int skc  = (tid & 7) ^ (srow & 7);         // inverse-swizzled chunk
    const int off0 = srow * 512 + skc * 8;           // global elem offset
    const int loff = tid * 8;                        // LDS elem offset

    const u16* GA = A  + (size_t)bm * 131072;        // 256 rows * 512
    const u16* GB = Wb + (size_t)bn * 131072;

    f32x4 acc[8][4] = {};

    // prologue: Ah0(0) Ah1(0) Bh0(0) Bh1(0) Ah0(1); allow Ah0(1) in flight
    stg2(GA,                 sm,                 off0, loff);
    stg2(GA + 65536,         sm + 8192,          off0, loff);
    stg2(GB,                 sm + 16384,         off0, loff);
    stg2(GB + 65536,         sm + 16384 + 8192,  off0, loff);
    stg2(GA + 64,            sm + 32768,         off0, loff);
    asm volatile("s_waitcnt vmcnt(2)" ::: "memory");
    __builtin_amdgcn_s_barrier();
    __builtin_amdgcn_sched_barrier(0);

    const int bhalf = wn >> 1;
    const int bsub  = (wn & 1) * 4096;  // 64 rows within B half

    for (int S = 0; S < NT; ++S) {
        const u16* pA = sm + (S & 1) * 32768 + wm * 8192 + l15 * 64;
        const u16* pB = sm + (S & 1) * 32768 + 16384 + bhalf * 8192 + bsub + l15 * 64;
        u16* nb = sm + ((S + 1) & 1) * 32768;   // next-tile buffer
        u16* cb = sm + (S & 1) * 32768;         // current buffer (Ah0(S+2))
        bf16x8 af[4][2], bA[2][2], bB[2][2];

        // ---------------- phase 0: read A rows 0-63 + B j0-1; stage Ah1(S+1)
#pragma unroll
        for (int i = 0; i < 4; ++i) {
            af[i][0] = *(const bf16x8*)&pA[i * 1024 + c0];
            af[i][1] = *(const bf16x8*)&pA[i * 1024 + c1];
        }
#pragma unroll
        for (int j = 0; j < 2; ++j) {
            bA[j][0] = *(const bf16x8*)&pB[j * 1024 + c0];
            bA[j][1] = *(const bf16x8*)&pB[j * 1024 + c1];
        }
        if (S + 1 < NT) stg2(GA + 65536 + (S + 1) * 64, nb + 8192, off0, loff);
        __builtin_amdgcn_s_barrier();
        asm volatile("s_waitcnt lgkmcnt(0)" ::: "memory");
        __builtin_amdgcn_sched_barrier(0);
        __builtin_amdgcn_s_setprio(1);
#pragma unroll
        for (int i = 0; i < 4; ++i)
#pragma unroll
            for (int j = 0; j < 2; ++j)
#pragma unroll
                for (int kk = 0; kk < 2; ++kk)
                    acc[i][j] = __builtin_amdgcn_mfma_f32_16x16x32_bf16(
                        af[i][kk], bA[j][kk], acc[i][j], 0, 0, 0);
        __builtin_amdgcn_s_setprio(0);
        __builtin_amdgcn_s_barrier();
        asm volatile("" ::: "memory");

        // ---------------- phase 1: read B j2-3; stage Bh0(S+1)
#pragma unroll
        for (int j = 0; j < 2; ++j) {
            bB[j][0] = *(const bf16x8*)&pB[(j + 2) * 1024 + c0];
            bB[j][1] = *(const bf16x8*)&pB[(j + 2) * 1024 + c1];
        }
        if (S + 1 < NT) stg2(GB + (S + 1) * 64, nb + 16384, off0, loff);
        __builtin_amdgcn_s_barrier();
        asm volatile("s_waitcnt lgkmcnt(0)" ::: "memory");
        __builtin_amdgcn_sched_barrier(0);
        __builtin_amdgcn_s_setprio(1);
#pragma unroll
        for (int i = 0; i < 4; ++i)
#pragma unroll
            for (int j = 0; j < 2; ++j)
#pragma unroll
                for (int kk = 0; kk < 2; ++kk)
                    acc[i][j + 2] = __builtin_amdgcn_mfma_f32_16x16x32_bf16(
                        af[i][kk], bB[j][kk], acc[i][j + 2], 0, 0, 0);
        __builtin_amdgcn_s_setprio(0);
        __builtin_amdgcn_s_barrier();
        asm volatile("" ::: "memory");

        // ---------------- phase 2: read A rows 64-127; stage Bh1(S+1)
#pragma unroll
        for (int i = 0; i < 4; ++i) {
            af[i][0] = *(const bf16x8*)&pA[(i + 4) * 1024 + c0];
            af[i][1] = *(const bf16x8*)&pA[(i + 4) * 1024 + c1];
        }
        if (S + 1 < NT) stg2(GB + 65536 + (S + 1) * 64, nb + 16384 + 8192, off0, loff);
        __builtin_amdgcn_s_barrier();
        asm volatile("s_waitcnt lgkmcnt(0)" ::: "memory");
        __builtin_amdgcn_sched_barrier(0);
        __builtin_amdgcn_s_setprio(1);
#pragma unroll
        for (int i = 0; i < 4; ++i)
#pragma unroll
            for (int j = 0; j < 2; ++j)
#pragma unroll
                for (int kk = 0; kk < 2; ++kk)
                    acc[i + 4][j + 2] = __builtin_amdgcn_mfma_f32_16x16x32_bf16(
                        af[i][kk], bB[j][kk], acc[i + 4][j + 2], 0, 0, 0);
        __builtin_amdgcn_s_setprio(0);
        __builtin_amdgcn_s_barrier();
        asm volatile("" ::: "memory");

        // ---------------- phase 3: no reads (bA live); stage Ah0(S+2)
        if (S + 2 < NT) stg2(GA + (S + 2) * 64, cb, off0, loff);
        __builtin_amdgcn_s_barrier();
        __builtin_amdgcn_s_setprio(1);
#pragma unroll
        for (int i = 0; i < 4; ++i)
#pragma unroll
            for (int j = 0; j < 2; ++j)
#pragma unroll
                for (int kk = 0; kk < 2; ++kk)
                    acc[i + 4][j] = __builtin_amdgcn_mfma_f32_16x16x32_bf16(
                        af[i][kk], bA[j][kk], acc[i + 4][j], 0, 0, 0);
        __builtin_amdgcn_s_setprio(0);
        // K-tile boundary: counted drain — keep newest half-tile in flight
        if (S + 2 < NT)      { asm volatile("s_waitcnt vmcnt(2)" ::: "memory"); }
        else if (S + 1 < NT) { asm volatile("s_waitcnt vmcnt(0)" ::: "memory"); }
        __builtin_amdgcn_s_barrier();
        asm volatile("" ::: "memory");
    }

    // epilogue: C/D layout col = lane&15, row = quad*4 + reg
    const int col0 = bn * 256 + wn * 64 + l15;
    const int rb   = bm * 256 + wm * 128 + quad * 4;
    float bv[4];
#pragma unroll
    for (int j = 0; j < 4; ++j) bv[j] = bias[col0 + j * 16];
#pragma unroll
    for (int i = 0; i < 8; ++i) {
#pragma unroll
        for (int r = 0; r < 4; ++r) {
            float* op = out + (size_t)(rb + i * 16 + r) * 1024 + col0;
#pragma unroll
            for (int j = 0; j < 4; ++j) op[j * 16] = acc[i][j][r] + bv[j];
        }
    }
}

// ---------------- Fallback (ws too small): compute tiles inline ------------
__global__ __launch_bounds__(256) void gemm_inl(const float* __restrict__ src,
                                                const float* __restrict__ tgt,
                                                const float* __restrict__ W,
                                                const float* __restrict__ bias,
                                                float* __restrict__ out) {
    __shared__ u16 lA[128 * 64];
    __shared__ u16 lB[128 * 64];
    const int tid  = threadIdx.x;
    const int bn   = blockIdx.x & 7;
    const int bm   = blockIdx.x >> 3;
    const int lane = tid & 63;
    const int wave = tid >> 6;
    const int wm   = wave >> 1, wn = wave & 1;
    const int l15  = lane & 15, quad = lane >> 4;

    f32x4 acc[4][4] = {};

    const int srow = tid >> 3;
    const int skc  = (tid & 7) * 8;

    const u16* pa = &lA[(wm * 64 + l15) * 64 + quad * 8];
    const u16* pb = &lB[(wn * 64 + l15) * 64 + quad * 8];

    for (int kt = 0; kt < 8; ++kt) {
        const int k0 = kt * 64;
#pragma unroll
        for (int r = 0; r < 4; ++r) {
            const int c   = r * 256 + tid;
            const int row = r * 32 + srow;
            int m = bm * 128 + row;
            int b = m / 40000;
            int rem = m - b * 40000;
            int t = rem / 100;
            int u = rem - t * 100;
            const float* sp = src + (size_t)(b * Tt + t) * 512 + k0 + skc;
            const float* gp = tgt + (size_t)(b * Uu + u) * 512 + k0 + skc;
            float4 s0 = *(const float4*)sp, s1 = *(const float4*)(sp + 4);
            float4 g0 = *(const float4*)gp, g1 = *(const float4*)(gp + 4);
            bf16x8 pk;
            pk[0] = (short)f2bf(tanhf(s0.x + g0.x));
            pk[1] = (short)f2bf(tanhf(s0.y + g0.y));
            pk[2] = (short)f2bf(tanhf(s0.z + g0.z));
            pk[3] = (short)f2bf(tanhf(s0.w + g0.w));
            pk[4] = (short)f2bf(tanhf(s1.x + g1.x));
            pk[5] = (short)f2bf(tanhf(s1.y + g1.y));
            pk[6] = (short)f2bf(tanhf(s1.z + g1.z));
            pk[7] = (short)f2bf(tanhf(s1.w + g1.w));
            *(bf16x8*)&lA[c * 8] = pk;
            const float* wp = W + (size_t)(bn * 128 + row) * 512 + k0 + skc;
            float4 w0 = *(const float4*)wp, w1 = *(const float4*)(wp + 4);
            bf16x8 wk;
            wk[0] = (short)f2bf(w0.x); wk[1] = (short)f2bf(w0.y);
            wk[2] = (short)f2bf(w0.z); wk[3] = (short)f2bf(w0.w);
            wk[4] = (short)f2bf(w1.x); wk[5] = (short)f2bf(w1.y);
            wk[6] = (short)f2bf(w1.z); wk[7] = (short)f2bf(w1.w);
            *(bf16x8*)&lB[c * 8] = wk;
        }
        __syncthreads();
#pragma unroll
        for (int kk = 0; kk < 2; ++kk) {
            bf16x8 af[4], bfr[4];
#pragma unroll
            for (int i = 0; i < 4; ++i)
                af[i] = *(const bf16x8*)&pa[i * 1024 + kk * 32];
#pragma unroll
            for (int j = 0; j < 4; ++j)
                bfr[j] = *(const bf16x8*)&pb[j * 1024 + kk * 32];
#pragma unroll
            for (int i = 0; i < 4; ++i)
#pragma unroll
                for (int j = 0; j < 4; ++j)
                    acc[i][j] = __builtin_amdgcn_mfma_f32_16x16x32_bf16(
                        af[i], bfr[j], acc[i][j], 0, 0, 0);
        }
        __syncthreads();
    }

    const int col0  = bn * 128 + wn * 64 + l15;
    const int rbase = bm * 128 + wm * 64 + quad * 4;
    float bv[4];
#pragma unroll
    for (int j = 0; j < 4; ++j) bv[j] = bias[col0 + j * 16];
#pragma unroll
    for (int i = 0; i < 4; ++i) {
#pragma unroll
        for (int r = 0; r < 4; ++r) {
            float* op = out + (size_t)(rbase + i * 16 + r) * 1024 + col0;
#pragma unroll
            for (int j = 0; j < 4; ++j) op[j * 16] = acc[i][j][r] + bv[j];
        }
    }
}

__global__ void lenout(const int* __restrict__ slen, const int* __restrict__ tlen,
                       float* __restrict__ out) {
    int i = threadIdx.x;
    if (i < 4)      out[OUT_ELEMS + i] = (float)slen[i];
    else if (i < 8) out[OUT_ELEMS + i] = (float)tlen[i - 4];
}

extern "C" void kernel_launch(void* const* d_in, const int* in_sizes, int n_in,
                              void* d_out, int out_size, void* d_ws, size_t ws_size,
                              hipStream_t stream) {
    const float* src  = (const float*)d_in[0];
    const int*   slen = (const int*)d_in[1];
    const float* tgt  = (const float*)d_in[2];
    const int*   tlen = (const int*)d_in[3];
    const float* W    = (const float*)d_in[4];
    const float* bias = (const float*)d_in[5];
    float* out = (float*)d_out;

    const size_t needA = (size_t)Mtot * Dd * 2;  // 163,840,000 B
    const size_t needW = (size_t)Vv * Dd * 2;    //   1,048,576 B

    if (d_ws != nullptr && ws_size >= needA + needW) {
        u16* Abf = (u16*)d_ws;
        u16* Wbf = (u16*)((char*)d_ws + needA);
        tanh_fuse<<<dim3(80000), dim3(256), 0, stream>>>(src, tgt, Abf);
        wconv<<<dim3(512), dim3(256), 0, stream>>>(W, Wbf, slen, tlen, out);
        gemm8<<<dim3(2500), dim3(512), 0, stream>>>(Abf, Wbf, bias, out);
    } else {
        lenout<<<dim3(1), dim3(64), 0, stream>>>(slen, tlen, out);
        gemm_inl<<<dim3(10000), dim3(256), 0, stream>>>(src, tgt, W, bias, out);
    }
}

// Round 3
// 803.813 us; speedup vs baseline: 1.1361x; 1.0241x over previous
//
#include <hip/hip_runtime.h>

// Problem constants (fixed by reference): B=4, T=400, U=100, D=512, V=1024
#define Bb 4
#define Tt 400
#define Uu 100
#define Dd 512
#define Vv 1024
#define Mtot (Bb * Tt * Uu)          // 160000 rows
#define OUT_ELEMS ((size_t)Mtot * Vv) // 163,840,000
#define NSTEP 80                      // persistent: 10 tiles x 8 K-steps

typedef unsigned short u16;
typedef unsigned int u32;
typedef short bf16x8 __attribute__((ext_vector_type(8)));
typedef float f32x4 __attribute__((ext_vector_type(4)));
typedef u16 u16x4 __attribute__((ext_vector_type(4)));

// float -> bf16 round-to-nearest-even (inputs finite; no NaN path needed)
__device__ __forceinline__ u16 f2bf(float x) {
    union { float f; u32 u; } v; v.f = x;
    u32 r = v.u + 0x7FFFu + ((v.u >> 16) & 1u);
    return (u16)(r >> 16);
}

// fast tanh: 1 - 2/(e^{2x}+1); |err| ~1e-6 << bf16 ulp. Clamp keeps e finite.
__device__ __forceinline__ float fast_tanh(float x) {
    float cx = fminf(9.0f, fmaxf(-9.0f, x));
    float e  = __expf(cx + cx);
    return 1.0f - __fdividef(2.0f, e + 1.0f);
}

// async global->LDS, 16 bytes/lane (dest must be wave-uniform base + lane*16)
__device__ __forceinline__ void async16(const void* g, void* l) {
    __builtin_amdgcn_global_load_lds(
        (const __attribute__((address_space(1))) u32*)g,
        (__attribute__((address_space(3))) u32*)l,
        16, 0, 0);
}

// ---------------- Phase 1: A[m,k] = bf16(tanh(src[b,t,k] + tgt[b,u,k])) ----
// 8 elems/thread, 16B stores. idx in [0, 10,240,000)
__global__ void tanh_fuse(const float* __restrict__ src,
                          const float* __restrict__ tgt,
                          u16* __restrict__ A) {
    int idx = blockIdx.x * 256 + threadIdx.x;
    int d8 = idx & 63;                           // 512/8 = 64 chunks per row
    int m  = idx >> 6;
    int b  = m / 40000;
    int r  = m - b * 40000;
    int t  = r / 100;
    int u  = r - t * 100;
    const float4* sp = (const float4*)src + (size_t)(b * Tt + t) * 128 + d8 * 2;
    const float4* gp = (const float4*)tgt + (size_t)(b * Uu + u) * 128 + d8 * 2;
    float4 s0 = sp[0], s1 = sp[1];
    float4 g0 = gp[0], g1 = gp[1];
    bf16x8 o;
    o[0] = (short)f2bf(fast_tanh(s0.x + g0.x));
    o[1] = (short)f2bf(fast_tanh(s0.y + g0.y));
    o[2] = (short)f2bf(fast_tanh(s0.z + g0.z));
    o[3] = (short)f2bf(fast_tanh(s0.w + g0.w));
    o[4] = (short)f2bf(fast_tanh(s1.x + g1.x));
    o[5] = (short)f2bf(fast_tanh(s1.y + g1.y));
    o[6] = (short)f2bf(fast_tanh(s1.z + g1.z));
    o[7] = (short)f2bf(fast_tanh(s1.w + g1.w));
    ((bf16x8*)A)[idx] = o;
}

// ---------------- W fp32 -> bf16, plus length pass-through outputs ---------
__global__ void wconv(const float* __restrict__ W, u16* __restrict__ Wb,
                      const int* __restrict__ slen, const int* __restrict__ tlen,
                      float* __restrict__ out) {
    int idx = blockIdx.x * 256 + threadIdx.x;   // 0 .. 131071
    float4 w = ((const float4*)W)[idx];
    u16x4 o;
    o.x = f2bf(w.x); o.y = f2bf(w.y); o.z = f2bf(w.z); o.w = f2bf(w.w);
    ((u16x4*)Wb)[idx] = o;
    if (idx < 4)      out[OUT_ELEMS + idx] = (float)slen[idx];
    else if (idx < 8) out[OUT_ELEMS + idx] = (float)tlen[idx - 4];
}

// ---------------- Phase 2: persistent 256x256 8-phase GEMM-BT --------------
// grid = 250 blocks, 1/CU (128 KiB LDS), each owns 10 consecutive wg-tiles.
// Global K-step g in [0,80): tile = g>>3, S = g&7.  The double-buffered
// stage/compute pipeline runs continuously across tile boundaries; per-tile
// epilogue (128 stores + acc re-zero) issues between barriers and drains into
// L2 while the next tile computes.  Counted vmcnt(2) at K-step boundaries.

// stage one 128x64 half-tile: 512 threads x 2 x 16B
__device__ __forceinline__ void stg2(const u16* g, u16* l, int off0, int loff) {
    async16(g + off0,         l + loff);          // rows 0..63 of half
    async16(g + off0 + 32768, l + loff + 4096);   // rows 64..127
}

__global__ __launch_bounds__(512, 2) void gemm8p(const u16* __restrict__ A,
                                                 const u16* __restrict__ Wb,
                                                 const float* __restrict__ bias,
                                                 float* __restrict__ out) {
    __shared__ u16 sm[65536];   // 128 KiB

    const int tid = threadIdx.x;
    const int b0  = blockIdx.x * 10;              // first wg-tile of chunk

    const int lane = tid & 63, wave = tid >> 6;
    const int wm = wave >> 2, wn = wave & 3;      // 2M x 4N waves
    const int l15 = lane & 15, quad = lane >> 4;
    const int sx = l15 & 7;                       // read-side swizzle key
    const int c0 = (quad ^ sx) * 8;               // kk=0 chunk offset (elems)
    const int c1 = ((4 | quad) ^ sx) * 8;         // kk=1 chunk offset

    // staging lane constants: chunk c = q*512+tid -> row=c>>3, slot=c&7
    const int srow = tid >> 3;                    // 0..63
    const int skc  = (tid & 7) ^ (srow & 7);      // inverse-swizzled chunk
    const int off0 = srow * 512 + skc * 8;        // global elem offset
    const int loff = tid * 8;                     // LDS elem offset

    const int bhalf = wn >> 1;
    const int bsub  = (wn & 1) * 4096;            // 64 rows within B half

    f32x4 acc[8][4] = {};

    // step x -> global half-tile base (row 0 of A/B tile, k-offset S*64)
    auto stepA = [&](int x) -> const u16* {
        int wg = b0 + (x >> 3);
        return A + (size_t)(wg >> 2) * 131072 + (x & 7) * 64;
    };
    auto stepB = [&](int x) -> const u16* {
        int wg = b0 + (x >> 3);
        return Wb + (size_t)(wg & 3) * 131072 + (x & 7) * 64;
    };

    // prologue: Ah0(0) Ah1(0) Bh0(0) Bh1(0) Ah0(1); keep Ah0(1) in flight
    stg2(stepA(0),          sm,                 off0, loff);
    stg2(stepA(0) + 65536,  sm + 8192,          off0, loff);
    stg2(stepB(0),          sm + 16384,         off0, loff);
    stg2(stepB(0) + 65536,  sm + 24576,         off0, loff);
    stg2(stepA(1),          sm + 32768,         off0, loff);
    asm volatile("s_waitcnt vmcnt(2)" ::: "memory");
    __builtin_amdgcn_s_barrier();
    __builtin_amdgcn_sched_barrier(0);

    for (int g = 0; g < NSTEP; ++g) {
        const int p = g & 1;
        const u16* pA = sm + p * 32768 + wm * 8192 + l15 * 64;
        const u16* pB = sm + p * 32768 + 16384 + bhalf * 8192 + bsub + l15 * 64;
        u16* nb = sm + (p ^ 1) * 32768;   // buffer for step g+1 halves
        u16* cb = sm + p * 32768;         // buffer for step g+2 Ah0
        bf16x8 af[4][2], bA[2][2], bB[2][2];

        // -------- phase 0: read A rows 0-63 + B j0-1; stage Ah1(g+1)
#pragma unroll
        for (int i = 0; i < 4; ++i) {
            af[i][0] = *(const bf16x8*)&pA[i * 1024 + c0];
            af[i][1] = *(const bf16x8*)&pA[i * 1024 + c1];
        }
#pragma unroll
        for (int j = 0; j < 2; ++j) {
            bA[j][0] = *(const bf16x8*)&pB[j * 1024 + c0];
            bA[j][1] = *(const bf16x8*)&pB[j * 1024 + c1];
        }
        if (g + 1 < NSTEP) stg2(stepA(g + 1) + 65536, nb + 8192, off0, loff);
        __builtin_amdgcn_s_barrier();
        asm volatile("s_waitcnt lgkmcnt(0)" ::: "memory");
        __builtin_amdgcn_sched_barrier(0);
        __builtin_amdgcn_s_setprio(1);
#pragma unroll
        for (int i = 0; i < 4; ++i)
#pragma unroll
            for (int j = 0; j < 2; ++j)
#pragma unroll
                for (int kk = 0; kk < 2; ++kk)
                    acc[i][j] = __builtin_amdgcn_mfma_f32_16x16x32_bf16(
                        af[i][kk], bA[j][kk], acc[i][j], 0, 0, 0);
        __builtin_amdgcn_s_setprio(0);
        __builtin_amdgcn_s_barrier();
        asm volatile("" ::: "memory");

        // -------- phase 1: read B j2-3; stage Bh0(g+1)
#pragma unroll
        for (int j = 0; j < 2; ++j) {
            bB[j][0] = *(const bf16x8*)&pB[(j + 2) * 1024 + c0];
            bB[j][1] = *(const bf16x8*)&pB[(j + 2) * 1024 + c1];
        }
        if (g + 1 < NSTEP) stg2(stepB(g + 1), nb + 16384, off0, loff);
        __builtin_amdgcn_s_barrier();
        asm volatile("s_waitcnt lgkmcnt(0)" ::: "memory");
        __builtin_amdgcn_sched_barrier(0);
        __builtin_amdgcn_s_setprio(1);
#pragma unroll
        for (int i = 0; i < 4; ++i)
#pragma unroll
            for (int j = 0; j < 2; ++j)
#pragma unroll
                for (int kk = 0; kk < 2; ++kk)
                    acc[i][j + 2] = __builtin_amdgcn_mfma_f32_16x16x32_bf16(
                        af[i][kk], bB[j][kk], acc[i][j + 2], 0, 0, 0);
        __builtin_amdgcn_s_setprio(0);
        __builtin_amdgcn_s_barrier();
        asm volatile("" ::: "memory");

        // -------- phase 2: read A rows 64-127; stage Bh1(g+1)
#pragma unroll
        for (int i = 0; i < 4; ++i) {
            af[i][0] = *(const bf16x8*)&pA[(i + 4) * 1024 + c0];
            af[i][1] = *(const bf16x8*)&pA[(i + 4) * 1024 + c1];
        }
        if (g + 1 < NSTEP) stg2(stepB(g + 1) + 65536, nb + 24576, off0, loff);
        __builtin_amdgcn_s_barrier();
        asm volatile("s_waitcnt lgkmcnt(0)" ::: "memory");
        __builtin_amdgcn_sched_barrier(0);
        __builtin_amdgcn_s_setprio(1);
#pragma unroll
        for (int i = 0; i < 4; ++i)
#pragma unroll
            for (int j = 0; j < 2; ++j)
#pragma unroll
                for (int kk = 0; kk < 2; ++kk)
                    acc[i + 4][j + 2] = __builtin_amdgcn_mfma_f32_16x16x32_bf16(
                        af[i][kk], bB[j][kk], acc[i + 4][j + 2], 0, 0, 0);
        __builtin_amdgcn_s_setprio(0);
        __builtin_amdgcn_s_barrier();
        asm volatile("" ::: "memory");

        // -------- phase 3: no reads (bA, af live); stage Ah0(g+2)
        if (g + 2 < NSTEP) stg2(stepA(g + 2), cb, off0, loff);
        __builtin_amdgcn_s_barrier();
        __builtin_amdgcn_s_setprio(1);
#pragma unroll
        for (int i = 0; i < 4; ++i)
#pragma unroll
            for (int j = 0; j < 2; ++j)
#pragma unroll
                for (int kk = 0; kk < 2; ++kk)
                    acc[i + 4][j] = __builtin_amdgcn_mfma_f32_16x16x32_bf16(
                        af[i][kk], bA[j][kk], acc[i + 4][j], 0, 0, 0);
        __builtin_amdgcn_s_setprio(0);
        // K-step boundary: counted drain — keep newest half-tile in flight
        if (g + 2 < NSTEP)      { asm volatile("s_waitcnt vmcnt(2)" ::: "memory"); }
        else                    { asm volatile("s_waitcnt vmcnt(0)" ::: "memory"); }
        __builtin_amdgcn_s_barrier();
        asm volatile("" ::: "memory");

        // -------- per-tile epilogue: store + re-zero acc; pipeline keeps going
        if ((g & 7) == 7) {
            const int wg = b0 + (g >> 3);
            const int bm = wg >> 2, bn = wg & 3;
            const int col0 = bn * 256 + wn * 64 + l15;
            const int rb   = bm * 256 + wm * 128 + quad * 4;
            float bv[4];
#pragma unroll
            for (int j = 0; j < 4; ++j) bv[j] = bias[col0 + j * 16];
#pragma unroll
            for (int i = 0; i < 8; ++i) {
#pragma unroll
                for (int r = 0; r < 4; ++r) {
                    float* op = out + (size_t)(rb + i * 16 + r) * 1024 + col0;
#pragma unroll
                    for (int j = 0; j < 4; ++j) op[j * 16] = acc[i][j][r] + bv[j];
                }
            }
            const f32x4 zz = {0.f, 0.f, 0.f, 0.f};
#pragma unroll
            for (int i = 0; i < 8; ++i)
#pragma unroll
                for (int j = 0; j < 4; ++j) acc[i][j] = zz;
        }
    }
}

// ---------------- Fallback (ws too small): compute tiles inline ------------
__global__ __launch_bounds__(256) void gemm_inl(const float* __restrict__ src,
                                                const float* __restrict__ tgt,
                                                const float* __restrict__ W,
                                                const float* __restrict__ bias,
                                                float* __restrict__ out) {
    __shared__ u16 lA[128 * 64];
    __shared__ u16 lB[128 * 64];
    const int tid  = threadIdx.x;
    const int bn   = blockIdx.x & 7;
    const int bm   = blockIdx.x >> 3;
    const int lane = tid & 63;
    const int wave = tid >> 6;
    const int wm   = wave >> 1, wn = wave & 1;
    const int l15  = lane & 15, quad = lane >> 4;

    f32x4 acc[4][4] = {};

    const int srow = tid >> 3;
    const int skc  = (tid & 7) * 8;

    const u16* pa = &lA[(wm * 64 + l15) * 64 + quad * 8];
    const u16* pb = &lB[(wn * 64 + l15) * 64 + quad * 8];

    for (int kt = 0; kt < 8; ++kt) {
        const int k0 = kt * 64;
#pragma unroll
        for (int r = 0; r < 4; ++r) {
            const int c   = r * 256 + tid;
            const int row = r * 32 + srow;
            int m = bm * 128 + row;
            int b = m / 40000;
            int rem = m - b * 40000;
            int t = rem / 100;
            int u = rem - t * 100;
            const float* sp = src + (size_t)(b * Tt + t) * 512 + k0 + skc;
            const float* gp = tgt + (size_t)(b * Uu + u) * 512 + k0 + skc;
            float4 s0 = *(const float4*)sp, s1 = *(const float4*)(sp + 4);
            float4 g0 = *(const float4*)gp, g1 = *(const float4*)(gp + 4);
            bf16x8 pk;
            pk[0] = (short)f2bf(fast_tanh(s0.x + g0.x));
            pk[1] = (short)f2bf(fast_tanh(s0.y + g0.y));
            pk[2] = (short)f2bf(fast_tanh(s0.z + g0.z));
            pk[3] = (short)f2bf(fast_tanh(s0.w + g0.w));
            pk[4] = (short)f2bf(fast_tanh(s1.x + g1.x));
            pk[5] = (short)f2bf(fast_tanh(s1.y + g1.y));
            pk[6] = (short)f2bf(fast_tanh(s1.z + g1.z));
            pk[7] = (short)f2bf(fast_tanh(s1.w + g1.w));
            *(bf16x8*)&lA[c * 8] = pk;
            const float* wp = W + (size_t)(bn * 128 + row) * 512 + k0 + skc;
            float4 w0 = *(const float4*)wp, w1 = *(const float4*)(wp + 4);
            bf16x8 wk;
            wk[0] = (short)f2bf(w0.x); wk[1] = (short)f2bf(w0.y);
            wk[2] = (short)f2bf(w0.z); wk[3] = (short)f2bf(w0.w);
            wk[4] = (short)f2bf(w1.x); wk[5] = (short)f2bf(w1.y);
            wk[6] = (short)f2bf(w1.z); wk[7] = (short)f2bf(w1.w);
            *(bf16x8*)&lB[c * 8] = wk;
        }
        __syncthreads();
#pragma unroll
        for (int kk = 0; kk < 2; ++kk) {
            bf16x8 af[4], bfr[4];
#pragma unroll
            for (int i = 0; i < 4; ++i)
                af[i] = *(const bf16x8*)&pa[i * 1024 + kk * 32];
#pragma unroll
            for (int j = 0; j < 4; ++j)
                bfr[j] = *(const bf16x8*)&pb[j * 1024 + kk * 32];
#pragma unroll
            for (int i = 0; i < 4; ++i)
#pragma unroll
                for (int j = 0; j < 4; ++j)
                    acc[i][j] = __builtin_amdgcn_mfma_f32_16x16x32_bf16(
                        af[i], bfr[j], acc[i][j], 0, 0, 0);
        }
        __syncthreads();
    }

    const int col0  = bn * 128 + wn * 64 + l15;
    const int rbase = bm * 128 + wm * 64 + quad * 4;
    float bv[4];
#pragma unroll
    for (int j = 0; j < 4; ++j) bv[j] = bias[col0 + j * 16];
#pragma unroll
    for (int i = 0; i < 4; ++i) {
#pragma unroll
        for (int r = 0; r < 4; ++r) {
            float* op = out + (size_t)(rbase + i * 16 + r) * 1024 + col0;
#pragma unroll
            for (int j = 0; j < 4; ++j) op[j * 16] = acc[i][j][r] + bv[j];
        }
    }
}

__global__ void lenout(const int* __restrict__ slen, const int* __restrict__ tlen,
                       float* __restrict__ out) {
    int i = threadIdx.x;
    if (i < 4)      out[OUT_ELEMS + i] = (float)slen[i];
    else if (i < 8) out[OUT_ELEMS + i] = (float)tlen[i - 4];
}

extern "C" void kernel_launch(void* const* d_in, const int* in_sizes, int n_in,
                              void* d_out, int out_size, void* d_ws, size_t ws_size,
                              hipStream_t stream) {
    const float* src  = (const float*)d_in[0];
    const int*   slen = (const int*)d_in[1];
    const float* tgt  = (const float*)d_in[2];
    const int*   tlen = (const int*)d_in[3];
    const float* W    = (const float*)d_in[4];
    const float* bias = (const float*)d_in[5];
    float* out = (float*)d_out;

    const size_t needA = (size_t)Mtot * Dd * 2;  // 163,840,000 B
    const size_t needW = (size_t)Vv * Dd * 2;    //   1,048,576 B

    if (d_ws != nullptr && ws_size >= needA + needW) {
        u16* Abf = (u16*)d_ws;
        u16* Wbf = (u16*)((char*)d_ws + needA);
        tanh_fuse<<<dim3(40000), dim3(256), 0, stream>>>(src, tgt, Abf);
        wconv<<<dim3(512), dim3(256), 0, stream>>>(W, Wbf, slen, tlen, out);
        gemm8p<<<dim3(250), dim3(512), 0, stream>>>(Abf, Wbf, bias, out);
    } else {
        lenout<<<dim3(1), dim3(64), 0, stream>>>(slen, tlen, out);
        gemm_inl<<<dim3(10000), dim3(256), 0, stream>>>(src, tgt, W, bias, out);
    }
}

// Round 4
// 800.867 us; speedup vs baseline: 1.1403x; 1.0037x over previous
//
#include <hip/hip_runtime.h>

// Problem constants (fixed by reference): B=4, T=400, U=100, D=512, V=1024
#define Bb 4
#define Tt 400
#define Uu 100
#define Dd 512
#define Vv 1024
#define Mtot (Bb * Tt * Uu)          // 160000 rows
#define OUT_ELEMS ((size_t)Mtot * Vv) // 163,840,000
#define NT 8                          // K-tiles: 512 / 64

typedef unsigned short u16;
typedef unsigned int u32;
typedef short bf16x8 __attribute__((ext_vector_type(8)));
typedef float f32x4 __attribute__((ext_vector_type(4)));
typedef u16 u16x4 __attribute__((ext_vector_type(4)));

// float -> bf16 round-to-nearest-even (inputs finite; no NaN path needed)
__device__ __forceinline__ u16 f2bf(float x) {
    union { float f; u32 u; } v; v.f = x;
    u32 r = v.u + 0x7FFFu + ((v.u >> 16) & 1u);
    return (u16)(r >> 16);
}

// fast tanh: 1 - 2/(e^{2x}+1); |err| ~1e-6 << bf16 ulp. Clamp keeps e finite.
__device__ __forceinline__ float fast_tanh(float x) {
    float cx = fminf(9.0f, fmaxf(-9.0f, x));
    float e  = __expf(cx + cx);
    return 1.0f - __fdividef(2.0f, e + 1.0f);
}

// async global->LDS, 16 bytes/lane (dest must be wave-uniform base + lane*16)
__device__ __forceinline__ void async16(const void* g, void* l) {
    __builtin_amdgcn_global_load_lds(
        (const __attribute__((address_space(1))) u32*)g,
        (__attribute__((address_space(3))) u32*)l,
        16, 0, 0);
}

// ---------------- Phase 1: A[m,k] = bf16(tanh(src[b,t,k] + tgt[b,u,k])) ----
// 8 elems/thread, 16B stores. idx in [0, 10,240,000)
__global__ void tanh_fuse(const float* __restrict__ src,
                          const float* __restrict__ tgt,
                          u16* __restrict__ A) {
    int idx = blockIdx.x * 256 + threadIdx.x;
    int d8 = idx & 63;                           // 512/8 = 64 chunks per row
    int m  = idx >> 6;
    int b  = m / 40000;
    int r  = m - b * 40000;
    int t  = r / 100;
    int u  = r - t * 100;
    const float4* sp = (const float4*)src + (size_t)(b * Tt + t) * 128 + d8 * 2;
    const float4* gp = (const float4*)tgt + (size_t)(b * Uu + u) * 128 + d8 * 2;
    float4 s0 = sp[0], s1 = sp[1];
    float4 g0 = gp[0], g1 = gp[1];
    bf16x8 o;
    o[0] = (short)f2bf(fast_tanh(s0.x + g0.x));
    o[1] = (short)f2bf(fast_tanh(s0.y + g0.y));
    o[2] = (short)f2bf(fast_tanh(s0.z + g0.z));
    o[3] = (short)f2bf(fast_tanh(s0.w + g0.w));
    o[4] = (short)f2bf(fast_tanh(s1.x + g1.x));
    o[5] = (short)f2bf(fast_tanh(s1.y + g1.y));
    o[6] = (short)f2bf(fast_tanh(s1.z + g1.z));
    o[7] = (short)f2bf(fast_tanh(s1.w + g1.w));
    ((bf16x8*)A)[idx] = o;
}

// ---------------- W fp32 -> bf16, plus length pass-through outputs ---------
__global__ void wconv(const float* __restrict__ W, u16* __restrict__ Wb,
                      const int* __restrict__ slen, const int* __restrict__ tlen,
                      float* __restrict__ out) {
    int idx = blockIdx.x * 256 + threadIdx.x;   // 0 .. 131071
    float4 w = ((const float4*)W)[idx];
    u16x4 o;
    o.x = f2bf(w.x); o.y = f2bf(w.y); o.z = f2bf(w.z); o.w = f2bf(w.w);
    ((u16x4*)Wb)[idx] = o;
    if (idx < 4)      out[OUT_ELEMS + idx] = (float)slen[idx];
    else if (idx < 8) out[OUT_ELEMS + idx] = (float)tlen[idx - 4];
}

// ---------------- Phase 2: 256x256 8-phase GEMM-BT (R1-verified) -----------
// C[m,v] = sum_k A[m,k]*Wb[v,k] + bias[v].  8 waves (2M x 4N), per-wave 128x64.
// LDS 128 KiB: 2 bufs x {A: 2 halves x 128x64, B: same}, bf16.
// XCD swizzle keeps the 4 bn-sharing blocks concurrent on one XCD -> A-tile
// fetched from HBM once, served from that XCD's L2 for the other 3 blocks.
// Counted vmcnt(2) at K-tile boundaries only (1 half-tile stays in flight).

// stage one 128x64 half-tile: 512 threads x 2 x 16B
__device__ __forceinline__ void stg2(const u16* g, u16* l, int off0, int loff) {
    async16(g + off0,         l + loff);          // rows 0..63 of half
    async16(g + off0 + 32768, l + loff + 4096);   // rows 64..127
}

__global__ __launch_bounds__(512, 2) void gemm8(const u16* __restrict__ A,
                                                const u16* __restrict__ Wb,
                                                const float* __restrict__ bias,
                                                float* __restrict__ out) {
    __shared__ u16 sm[65536];   // 128 KiB

    const int tid = threadIdx.x;
    // bijective XCD swizzle: 2500 wgs, q=312, r=4 (m204 formula)
    const int orig = blockIdx.x;
    const int xcd = orig & 7, loc = orig >> 3;
    const int wg = (xcd < 4 ? xcd * 313 : 1252 + (xcd - 4) * 312) + loc;
    const int bm = wg >> 2;        // 0..624
    const int bn = wg & 3;         // 0..3

    const int lane = tid & 63, wave = tid >> 6;
    const int wm = wave >> 2, wn = wave & 3;       // 2M x 4N waves
    const int l15 = lane & 15, quad = lane >> 4;
    const int sx = l15 & 7;                        // read-side swizzle key
    const int c0 = (quad ^ sx) * 8;                // kk=0 chunk offset (elems)
    const int c1 = ((4 | quad) ^ sx) * 8;          // kk=1 chunk offset

    // staging lane constants: chunk c = q*512+tid -> row=c>>3, slot=c&7
    const int srow = tid >> 3;                       // 0..63
    const int skc  = (tid & 7) ^ (srow & 7);         // inverse-swizzled chunk
    const int off0 = srow * 512 + skc * 8;           // global elem offset
    const int loff = tid * 8;                        // LDS elem offset

    const u16* GA = A  + (size_t)bm * 131072;        // 256 rows * 512
    const u16* GB = Wb + (size_t)bn * 131072;

    f32x4 acc[8][4] = {};

    // prologue: Ah0(0) Ah1(0) Bh0(0) Bh1(0) Ah0(1); allow Ah0(1) in flight
    stg2(GA,                 sm,                 off0, loff);
    stg2(GA + 65536,         sm + 8192,          off0, loff);
    stg2(GB,                 sm + 16384,         off0, loff);
    stg2(GB + 65536,         sm + 16384 + 8192,  off0, loff);
    stg2(GA + 64,            sm + 32768,         off0, loff);
    asm volatile("s_waitcnt vmcnt(2)" ::: "memory");
    __builtin_amdgcn_s_barrier();
    __builtin_amdgcn_sched_barrier(0);

    const int bhalf = wn >> 1;
    const int bsub  = (wn & 1) * 4096;  // 64 rows within B half

    for (int S = 0; S < NT; ++S) {
        const u16* pA = sm + (S & 1) * 32768 + wm * 8192 + l15 * 64;
        const u16* pB = sm + (S & 1) * 32768 + 16384 + bhalf * 8192 + bsub + l15 * 64;
        u16* nb = sm + ((S + 1) & 1) * 32768;   // next-tile buffer
        u16* cb = sm + (S & 1) * 32768;         // current buffer (Ah0(S+2))
        bf16x8 af[4][2], bA[2][2], bB[2][2];

        // ---------------- phase 0: read A rows 0-63 + B j0-1; stage Ah1(S+1)
#pragma unroll
        for (int i = 0; i < 4; ++i) {
            af[i][0] = *(const bf16x8*)&pA[i * 1024 + c0];
            af[i][1] = *(const bf16x8*)&pA[i * 1024 + c1];
        }
#pragma unroll
        for (int j = 0; j < 2; ++j) {
            bA[j][0] = *(const bf16x8*)&pB[j * 1024 + c0];
            bA[j][1] = *(const bf16x8*)&pB[j * 1024 + c1];
        }
        if (S + 1 < NT) stg2(GA + 65536 + (S + 1) * 64, nb + 8192, off0, loff);
        __builtin_amdgcn_s_barrier();
        asm volatile("s_waitcnt lgkmcnt(0)" ::: "memory");
        __builtin_amdgcn_sched_barrier(0);
        __builtin_amdgcn_s_setprio(1);
#pragma unroll
        for (int i = 0; i < 4; ++i)
#pragma unroll
            for (int j = 0; j < 2; ++j)
#pragma unroll
                for (int kk = 0; kk < 2; ++kk)
                    acc[i][j] = __builtin_amdgcn_mfma_f32_16x16x32_bf16(
                        af[i][kk], bA[j][kk], acc[i][j], 0, 0, 0);
        __builtin_amdgcn_s_setprio(0);
        __builtin_amdgcn_s_barrier();
        asm volatile("" ::: "memory");

        // ---------------- phase 1: read B j2-3; stage Bh0(S+1)
#pragma unroll
        for (int j = 0; j < 2; ++j) {
            bB[j][0] = *(const bf16x8*)&pB[(j + 2) * 1024 + c0];
            bB[j][1] = *(const bf16x8*)&pB[(j + 2) * 1024 + c1];
        }
        if (S + 1 < NT) stg2(GB + (S + 1) * 64, nb + 16384, off0, loff);
        __builtin_amdgcn_s_barrier();
        asm volatile("s_waitcnt lgkmcnt(0)" ::: "memory");
        __builtin_amdgcn_sched_barrier(0);
        __builtin_amdgcn_s_setprio(1);
#pragma unroll
        for (int i = 0; i < 4; ++i)
#pragma unroll
            for (int j = 0; j < 2; ++j)
#pragma unroll
                for (int kk = 0; kk < 2; ++kk)
                    acc[i][j + 2] = __builtin_amdgcn_mfma_f32_16x16x32_bf16(
                        af[i][kk], bB[j][kk], acc[i][j + 2], 0, 0, 0);
        __builtin_amdgcn_s_setprio(0);
        __builtin_amdgcn_s_barrier();
        asm volatile("" ::: "memory");

        // ---------------- phase 2: read A rows 64-127; stage Bh1(S+1)
#pragma unroll
        for (int i = 0; i < 4; ++i) {
            af[i][0] = *(const bf16x8*)&pA[(i + 4) * 1024 + c0];
            af[i][1] = *(const bf16x8*)&pA[(i + 4) * 1024 + c1];
        }
        if (S + 1 < NT) stg2(GB + 65536 + (S + 1) * 64, nb + 16384 + 8192, off0, loff);
        __builtin_amdgcn_s_barrier();
        asm volatile("s_waitcnt lgkmcnt(0)" ::: "memory");
        __builtin_amdgcn_sched_barrier(0);
        __builtin_amdgcn_s_setprio(1);
#pragma unroll
        for (int i = 0; i < 4; ++i)
#pragma unroll
            for (int j = 0; j < 2; ++j)
#pragma unroll
                for (int kk = 0; kk < 2; ++kk)
                    acc[i + 4][j + 2] = __builtin_amdgcn_mfma_f32_16x16x32_bf16(
                        af[i][kk], bB[j][kk], acc[i + 4][j + 2], 0, 0, 0);
        __builtin_amdgcn_s_setprio(0);
        __builtin_amdgcn_s_barrier();
        asm volatile("" ::: "memory");

        // ---------------- phase 3: no reads (bA live); stage Ah0(S+2)
        if (S + 2 < NT) stg2(GA + (S + 2) * 64, cb, off0, loff);
        __builtin_amdgcn_s_barrier();
        __builtin_amdgcn_s_setprio(1);
#pragma unroll
        for (int i = 0; i < 4; ++i)
#pragma unroll
            for (int j = 0; j < 2; ++j)
#pragma unroll
                for (int kk = 0; kk < 2; ++kk)
                    acc[i + 4][j] = __builtin_amdgcn_mfma_f32_16x16x32_bf16(
                        af[i][kk], bA[j][kk], acc[i + 4][j], 0, 0, 0);
        __builtin_amdgcn_s_setprio(0);
        // K-tile boundary: counted drain — keep newest half-tile in flight
        if (S + 2 < NT)      { asm volatile("s_waitcnt vmcnt(2)" ::: "memory"); }
        else if (S + 1 < NT) { asm volatile("s_waitcnt vmcnt(0)" ::: "memory"); }
        __builtin_amdgcn_s_barrier();
        asm volatile("" ::: "memory");
    }

    // epilogue: C/D layout col = lane&15, row = quad*4 + reg
    const int col0 = bn * 256 + wn * 64 + l15;
    const int rb   = bm * 256 + wm * 128 + quad * 4;
    float bv[4];
#pragma unroll
    for (int j = 0; j < 4; ++j) bv[j] = bias[col0 + j * 16];
#pragma unroll
    for (int i = 0; i < 8; ++i) {
#pragma unroll
        for (int r = 0; r < 4; ++r) {
            float* op = out + (size_t)(rb + i * 16 + r) * 1024 + col0;
#pragma unroll
            for (int j = 0; j < 4; ++j) op[j * 16] = acc[i][j][r] + bv[j];
        }
    }
}

// ---------------- Fallback (ws too small): compute tiles inline ------------
__global__ __launch_bounds__(256) void gemm_inl(const float* __restrict__ src,
                                                const float* __restrict__ tgt,
                                                const float* __restrict__ W,
                                                const float* __restrict__ bias,
                                                float* __restrict__ out) {
    __shared__ u16 lA[128 * 64];
    __shared__ u16 lB[128 * 64];
    const int tid  = threadIdx.x;
    const int bn   = blockIdx.x & 7;
    const int bm   = blockIdx.x >> 3;
    const int lane = tid & 63;
    const int wave = tid >> 6;
    const int wm   = wave >> 1, wn = wave & 1;
    const int l15  = lane & 15, quad = lane >> 4;

    f32x4 acc[4][4] = {};

    const int srow = tid >> 3;
    const int skc  = (tid & 7) * 8;

    const u16* pa = &lA[(wm * 64 + l15) * 64 + quad * 8];
    const u16* pb = &lB[(wn * 64 + l15) * 64 + quad * 8];

    for (int kt = 0; kt < 8; ++kt) {
        const int k0 = kt * 64;
#pragma unroll
        for (int r = 0; r < 4; ++r) {
            const int c   = r * 256 + tid;
            const int row = r * 32 + srow;
            int m = bm * 128 + row;
            int b = m / 40000;
            int rem = m - b * 40000;
            int t = rem / 100;
            int u = rem - t * 100;
            const float* sp = src + (size_t)(b * Tt + t) * 512 + k0 + skc;
            const float* gp = tgt + (size_t)(b * Uu + u) * 512 + k0 + skc;
            float4 s0 = *(const float4*)sp, s1 = *(const float4*)(sp + 4);
            float4 g0 = *(const float4*)gp, g1 = *(const float4*)(gp + 4);
            bf16x8 pk;
            pk[0] = (short)f2bf(fast_tanh(s0.x + g0.x));
            pk[1] = (short)f2bf(fast_tanh(s0.y + g0.y));
            pk[2] = (short)f2bf(fast_tanh(s0.z + g0.z));
            pk[3] = (short)f2bf(fast_tanh(s0.w + g0.w));
            pk[4] = (short)f2bf(fast_tanh(s1.x + g1.x));
            pk[5] = (short)f2bf(fast_tanh(s1.y + g1.y));
            pk[6] = (short)f2bf(fast_tanh(s1.z + g1.z));
            pk[7] = (short)f2bf(fast_tanh(s1.w + g1.w));
            *(bf16x8*)&lA[c * 8] = pk;
            const float* wp = W + (size_t)(bn * 128 + row) * 512 + k0 + skc;
            float4 w0 = *(const float4*)wp, w1 = *(const float4*)(wp + 4);
            bf16x8 wk;
            wk[0] = (short)f2bf(w0.x); wk[1] = (short)f2bf(w0.y);
            wk[2] = (short)f2bf(w0.z); wk[3] = (short)f2bf(w0.w);
            wk[4] = (short)f2bf(w1.x); wk[5] = (short)f2bf(w1.y);
            wk[6] = (short)f2bf(w1.z); wk[7] = (short)f2bf(w1.w);
            *(bf16x8*)&lB[c * 8] = wk;
        }
        __syncthreads();
#pragma unroll
        for (int kk = 0; kk < 2; ++kk) {
            bf16x8 af[4], bfr[4];
#pragma unroll
            for (int i = 0; i < 4; ++i)
                af[i] = *(const bf16x8*)&pa[i * 1024 + kk * 32];
#pragma unroll
            for (int j = 0; j < 4; ++j)
                bfr[j] = *(const bf16x8*)&pb[j * 1024 + kk * 32];
#pragma unroll
            for (int i = 0; i < 4; ++i)
#pragma unroll
                for (int j = 0; j < 4; ++j)
                    acc[i][j] = __builtin_amdgcn_mfma_f32_16x16x32_bf16(
                        af[i], bfr[j], acc[i][j], 0, 0, 0);
        }
        __syncthreads();
    }

    const int col0  = bn * 128 + wn * 64 + l15;
    const int rbase = bm * 128 + wm * 64 + quad * 4;
    float bv[4];
#pragma unroll
    for (int j = 0; j < 4; ++j) bv[j] = bias[col0 + j * 16];
#pragma unroll
    for (int i = 0; i < 4; ++i) {
#pragma unroll
        for (int r = 0; r < 4; ++r) {
            float* op = out + (size_t)(rbase + i * 16 + r) * 1024 + col0;
#pragma unroll
            for (int j = 0; j < 4; ++j) op[j * 16] = acc[i][j][r] + bv[j];
        }
    }
}

__global__ void lenout(const int* __restrict__ slen, const int* __restrict__ tlen,
                       float* __restrict__ out) {
    int i = threadIdx.x;
    if (i < 4)      out[OUT_ELEMS + i] = (float)slen[i];
    else if (i < 8) out[OUT_ELEMS + i] = (float)tlen[i - 4];
}

extern "C" void kernel_launch(void* const* d_in, const int* in_sizes, int n_in,
                              void* d_out, int out_size, void* d_ws, size_t ws_size,
                              hipStream_t stream) {
    const float* src  = (const float*)d_in[0];
    const int*   slen = (const int*)d_in[1];
    const float* tgt  = (const float*)d_in[2];
    const int*   tlen = (const int*)d_in[3];
    const float* W    = (const float*)d_in[4];
    const float* bias = (const float*)d_in[5];
    float* out = (float*)d_out;

    const size_t needA = (size_t)Mtot * Dd * 2;  // 163,840,000 B
    const size_t needW = (size_t)Vv * Dd * 2;    //   1,048,576 B

    if (d_ws != nullptr && ws_size >= needA + needW) {
        u16* Abf = (u16*)d_ws;
        u16* Wbf = (u16*)((char*)d_ws + needA);
        tanh_fuse<<<dim3(40000), dim3(256), 0, stream>>>(src, tgt, Abf);
        wconv<<<dim3(512), dim3(256), 0, stream>>>(W, Wbf, slen, tlen, out);
        gemm8<<<dim3(2500), dim3(512), 0, stream>>>(Abf, Wbf, bias, out);
    } else {
        lenout<<<dim3(1), dim3(64), 0, stream>>>(slen, tlen, out);
        gemm_inl<<<dim3(10000), dim3(256), 0, stream>>>(src, tgt, W, bias, out);
    }
}